// Round 18
// baseline (944.415 us; speedup 1.0000x reference)
//
#include <hip/hip_runtime.h>
#include <hip/hip_bf16.h>
#include <stdint.h>

#define M_ROWS 300000
#define NB_DEF 4688

typedef __attribute__((ext_vector_type(8)))  short bf16x8;
typedef __attribute__((ext_vector_type(16))) float f32x16;
typedef __attribute__((ext_vector_type(4)))  float f32x4;

union U4 { uint4 u; bf16x8 h; unsigned short us[8]; };

__device__ __forceinline__ unsigned short f2bf(float f) {
  union { float f; uint32_t u; } v; v.f = f;
  uint32_t r = v.u + 0x7fffu + ((v.u >> 16) & 1u);
  return (unsigned short)(r >> 16);
}
__device__ __forceinline__ uint32_t pk2(float lo, float hi) {
  return (uint32_t)f2bf(lo) | ((uint32_t)f2bf(hi) << 16);
}
__device__ __forceinline__ f32x4 ntload4(const float* p) {
  return __builtin_nontemporal_load((const f32x4*)p);
}
__device__ __forceinline__ void ntstore4(float* p, f32x4 v) {
  __builtin_nontemporal_store(v, (f32x4*)p);
}
__device__ __forceinline__ bool bit_set(const uint32_t* bm, int r) {
  return (bm[r >> 5] >> (r & 31)) & 1u;
}

// ---- packed weight tile table (tiles of 32 cols x 16 k, 1 KiB each) ----
#define T_SP 0
#define T_ST 64
#define T_P1 128
#define T_P2 256
#define T_R1 272
#define T_R2 400
#define T_S1 416
#define T_S2 544
#define T_W1 576
#define T_W2 704
#define T_M1 720
#define T_M2 848
#define T_TOT 864

__global__ void prep_w(const float* Wsp, const float* Wst, const float* Wp1, const float* Wp2,
                       const float* Wr1, const float* Wr2, const float* Ws1, const float* Ws2,
                       const float* Ww1, const float* Ww2, const float* Wm1, const float* Wm2,
                       uint4* ws) {
  int b = blockIdx.x, l = threadIdx.x;
  const int starts[12] = {T_SP,T_ST,T_P1,T_P2,T_R1,T_R2,T_S1,T_S2,T_W1,T_W2,T_M1,T_M2};
  const int Ks[12]     = {128,128,256,256,256,256,256,256,256,256,256,256};
  const int Cos[12]    = {256,256,256,9,256,4,256,48,256,1,256,1};
  const float* Wp[12]  = {Wsp,Wst,Wp1,Wp2,Wr1,Wr2,Ws1,Ws2,Ww1,Ww2,Wm1,Wm2};
  int m = 0;
  #pragma unroll
  for (int i = 1; i < 12; ++i) if (b >= starts[i]) m = i;
  int local = b - starts[m];
  int KT = Ks[m] >> 4;
  int n0 = local / KT, k0 = local - n0 * KT;
  int col = n0 * 32 + (l & 31);
  int kbase = k0 * 16 + (l >> 5) * 8;
  const float* W = Wp[m];
  int Co = Cos[m];
  U4 pk;
  #pragma unroll
  for (int j = 0; j < 8; ++j) {
    float v = (col < Co) ? W[(size_t)(kbase + j) * Co + col] : 0.0f;
    pk.us[j] = f2bf(v);
  }
  ws[(size_t)b * 64 + l] = pk.u;
}

// ---- bitmap of indexed rows ----
__global__ void bm_zero(uint32_t* bm) { bm[blockIdx.x * 256 + threadIdx.x] = 0u; }
__global__ void bm_set(const int* idx, uint32_t* bm) {
  int i = blockIdx.x * 256 + threadIdx.x;
  if (i < M_ROWS) { int g = idx[i]; atomicOr(&bm[g >> 5], 1u << (g & 31)); }
}

// ---- fused MLP kernel: 64 rows/block, 8 waves, swapped MFMA, fused copy slices ----
#define LSTR 512
__device__ __forceinline__ int lds_addr(int row, int cb) {
  return row * LSTR + (cb ^ ((row & 15) << 4));
}

__device__ __forceinline__ void loadX(const float* grid, int row0, int t, char* buf) {
  #pragma unroll
  for (int i = 0; i < 4; ++i) {
    int fi = i * 512 + t;
    int row = fi >> 5;
    int c4 = fi & 31;
    int gr = row0 + row; gr = gr < M_ROWS ? gr : (M_ROWS - 1);
    f32x4 v = ntload4(grid + (size_t)gr * 128 + c4 * 4);
    ushort4 p;
    p.x = f2bf(v.x); p.y = f2bf(v.y); p.z = f2bf(v.z); p.w = f2bf(v.w);
    *(ushort4*)(buf + lds_addr(row, c4 * 8)) = p;
  }
}

__device__ __forceinline__ void pre8(U4 (&d)[8], const uint4* base, int lane) {
  #pragma unroll
  for (int i = 0; i < 8; ++i) d[i].u = base[(size_t)i * 64 + lane];
}
__device__ __forceinline__ void pre4(U4 (&d)[8], const uint4* base, int lane) {
  #pragma unroll
  for (int i = 0; i < 4; ++i) d[i].u = base[(size_t)i * 64 + lane];
}
__device__ __forceinline__ void pre_s2(U4 (&d)[8], const uint4* wt, int kq, int lane) {
  #pragma unroll
  for (int kk = 0; kk < 4; ++kk)
    #pragma unroll
    for (int n = 0; n < 2; ++n)
      d[kk * 2 + n].u = wt[(size_t)((n * 16 + kq * 4 + kk) * 64) + lane];
}

__device__ __forceinline__ void mm_big8T(U4 (&b)[8], const char* inb, int k0, int arow, int khalf,
                                         f32x16& acc0, f32x16& acc1) {
  #pragma unroll
  for (int k = 0; k < 8; ++k) {
    bf16x8 x0 = *(const bf16x8*)(inb + lds_addr(arow, (k0 + k) * 32 + khalf));
    bf16x8 x1 = *(const bf16x8*)(inb + lds_addr(32 + arow, (k0 + k) * 32 + khalf));
    acc0 = __builtin_amdgcn_mfma_f32_32x32x16_bf16(b[k].h, x0, acc0, 0, 0, 0);
    acc1 = __builtin_amdgcn_mfma_f32_32x32x16_bf16(b[k].h, x1, acc1, 0, 0, 0);
  }
}

__device__ __forceinline__ void store_actT(char* outb, const float* bias, int wave, int lane,
                                           const f32x16& acc0, const f32x16& acc1) {
  const int xr = lane & 31;
  const int cb0 = wave * 32 + 4 * (lane >> 5);
  #pragma unroll
  for (int run = 0; run < 4; ++run) {
    const int c0 = cb0 + 8 * run;
    const float4 bv = *(const float4*)(bias + c0);
    uint2 w0, w1;
    w0.x = pk2(fmaxf(acc0[run * 4 + 0] + bv.x, 0.0f), fmaxf(acc0[run * 4 + 1] + bv.y, 0.0f));
    w0.y = pk2(fmaxf(acc0[run * 4 + 2] + bv.z, 0.0f), fmaxf(acc0[run * 4 + 3] + bv.w, 0.0f));
    w1.x = pk2(fmaxf(acc1[run * 4 + 0] + bv.x, 0.0f), fmaxf(acc1[run * 4 + 1] + bv.y, 0.0f));
    w1.y = pk2(fmaxf(acc1[run * 4 + 2] + bv.z, 0.0f), fmaxf(acc1[run * 4 + 3] + bv.w, 0.0f));
    *(uint2*)(outb + lds_addr(xr, c0 * 2)) = w0;
    *(uint2*)(outb + lds_addr(32 + xr, c0 * 2)) = w1;
  }
}

__device__ __forceinline__ void mm_head1(U4 (&b)[8], const char* inb, int rg, int kq, int khalf,
                                         int lane, f32x16& acc) {
  const int arow = rg * 32 + (lane & 31);
  #pragma unroll
  for (int kk = 0; kk < 4; ++kk) {
    bf16x8 a = *(const bf16x8*)(inb + lds_addr(arow, (kq * 4 + kk) * 32 + khalf));
    acc = __builtin_amdgcn_mfma_f32_32x32x16_bf16(a, b[kk].h, acc, 0, 0, 0);
  }
}

template<int COLS>
__device__ __forceinline__ void head_atomic(float* outsm, int rg, int lane, const f32x16& acc) {
  int col = lane & 31;
  if (col < COLS) {
    #pragma unroll
    for (int q = 0; q < 16; ++q) {
      int row = rg * 32 + (q & 3) + 8 * (q >> 2) + 4 * (lane >> 5);
      atomicAdd(&outsm[row * COLS + col], acc[q]);
    }
  }
}

__device__ __forceinline__ void rot_atomic_global(const f32x16& acc, int rg, int kq, int lane,
                                                  const int* sidx, int row0, const float* b_r2,
                                                  float* out) {
  int col = lane & 31;
  if (col < 4) {
    float bb = (kq == 0) ? b_r2[col] : 0.0f;
    #pragma unroll
    for (int q = 0; q < 16; ++q) {
      int row = rg * 32 + (q & 3) + 8 * (q >> 2) + 4 * (lane >> 5);
      if (row0 + row < M_ROWS) {
        atomicAdd(out + 1800000 + (size_t)sidx[row] * 4 + col, acc[q] + bb);
      }
    }
  }
}

__device__ __forceinline__ void shs_atomic_global(const f32x16& a0, const f32x16& a1,
                                                  int rg, int kq, int lane,
                                                  const int* sidx, int row0, const float* b_s2,
                                                  float* out) {
  int c = lane & 31;
  float bb0 = (kq == 0) ? b_s2[c] : 0.0f;
  float bb1 = (kq == 0 && c < 16) ? b_s2[32 + c] : 0.0f;
  #pragma unroll
  for (int q = 0; q < 16; ++q) {
    int row = rg * 32 + (q & 3) + 8 * (q >> 2) + 4 * (lane >> 5);
    if (row0 + row < M_ROWS) {
      size_t base = 4800000 + (size_t)sidx[row] * 48;
      atomicAdd(out + base + c, a0[q] + bb0);
      if (c < 16) atomicAdd(out + base + 32 + c, a1[q] + bb1);
    }
  }
}

__global__ void __launch_bounds__(512, 4) deform_main(
    const float* grid_sp, const float* grid_st, const int* idx,
    const float* rays, const float* rotq, const float* shs_in,
    const float* time_emb, const float* h_emb,
    const uint4* ws, const uint32_t* bm,
    const float* b_sp, const float* b_st, const float* b_p1, const float* b_p2,
    const float* b_r1, const float* b_r2, const float* b_s1, const float* b_s2,
    const float* b_w1, const float* b_w2, const float* b_m1, const float* b_m2,
    float* out) {
  __shared__ char bufA[32768];
  __shared__ char bufB[32768];
  __shared__ float smf[704];   // dx [0,576) | w [576,640) | mu [640,704)
  __shared__ int sidx[64];
  float* dxb = smf;
  float* wb  = smf + 576;
  float* mub = smf + 640;

  const int t = threadIdx.x;
  const int lane = t & 63;
  const int wave = t >> 6;
  const int rg = wave & 1;
  const int kq = wave >> 1;
  const int arow = lane & 31;
  const int khalf = (lane >> 5) * 16;
  const int bid = blockIdx.x;
  const int row0 = bid * 64;
  const float tt = time_emb[0];

  U4 b0[8], b1[8];
  pre8(b0, ws + (size_t)(T_SP + wave * 8) * 64, lane);

  // P0: idx hoist, zero small accumulators, stage X_sp -> A
  if (t < 64) { int gr = row0 + t; sidx[t] = idx[gr < M_ROWS ? gr : (M_ROWS - 1)]; }
  if (t < 512) smf[t] = 0.0f;
  if (t < 192) smf[512 + t] = 0.0f;
  loadX(grid_sp, row0, t, bufA);
  __syncthreads();

  // P1: L_sp  A -> B (K=128) ; base-store rot/shs for own rows (plain stores -> L2)
  {
    f32x16 a0 = (f32x16)0.0f, a1 = (f32x16)0.0f;
    pre8(b1, ws + (size_t)(T_P1 + wave * 16) * 64, lane);
    if (t < 64 && row0 + t < M_ROWS) {
      int g = sidx[t];
      *(float4*)(out + 1800000 + (size_t)g * 4) = *(const float4*)(rotq + (size_t)g * 4);
    }
    #pragma unroll
    for (int i = 0; i < 2; ++i) {
      int e = i * 512 + t;
      if (e < 768) {
        int r = e / 12, c = e - r * 12;
        if (row0 + r < M_ROWS) {
          int g = sidx[r];
          *(float4*)(out + 4800000 + (size_t)g * 48 + c * 4) =
              *(const float4*)(shs_in + (size_t)g * 48 + c * 4);
        }
      }
    }
    __builtin_amdgcn_s_setprio(1);
    mm_big8T(b0, bufA, 0, arow, khalf, a0, a1);
    __builtin_amdgcn_s_setprio(0);
    store_actT(bufB, b_sp, wave, lane, a0, a1);
  }
  __syncthreads();

  // P2: L_p1  B -> A (K=256) ; copy shs slice part 1 (bitmap-skip)
  {
    f32x16 a0 = (f32x16)0.0f, a1 = (f32x16)0.0f;
    pre8(b0, ws + (size_t)(T_P1 + wave * 16 + 8) * 64, lane);
    {
      long long c0 = (long long)bid * 1536;
      #pragma unroll
      for (int i = 0; i < 2; ++i) {
        int j = i * 512 + t;
        if (j < 768) {
          long long c = c0 + j;
          if (c < 7200000) {
            int r = (int)(c / 12);
            if (!bit_set(bm, r)) ntstore4(out + 4800000 + c * 4, ntload4(shs_in + c * 4));
          }
        }
      }
    }
    __builtin_amdgcn_s_setprio(1);
    mm_big8T(b1, bufB, 0, arow, khalf, a0, a1);
    __builtin_amdgcn_s_setprio(0);
    pre4(b1, ws + (size_t)(T_P2 + kq * 4) * 64, lane);
    __builtin_amdgcn_s_setprio(1);
    mm_big8T(b0, bufB, 8, arow, khalf, a0, a1);
    __builtin_amdgcn_s_setprio(0);
    store_actT(bufA, b_p1, wave, lane, a0, a1);
  }
  __syncthreads();

  // P3: H_p2 dx head (reads A=hp)
  {
    f32x16 hacc = (f32x16)0.0f;
    pre8(b0, ws + (size_t)(T_W1 + wave * 16) * 64, lane);
    __builtin_amdgcn_s_setprio(1);
    mm_head1(b1, bufA, rg, kq, khalf, lane, hacc);
    __builtin_amdgcn_s_setprio(0);
    head_atomic<9>(dxb, rg, lane, hacc);
  }
  __syncthreads();

  // P4: L_w1  B -> A ; copy shs slice part 2
  {
    f32x16 a0 = (f32x16)0.0f, a1 = (f32x16)0.0f;
    pre8(b1, ws + (size_t)(T_W1 + wave * 16 + 8) * 64, lane);
    {
      long long c0 = (long long)bid * 1536 + 768;
      #pragma unroll
      for (int i = 0; i < 2; ++i) {
        int j = i * 512 + t;
        if (j < 768) {
          long long c = c0 + j;
          if (c < 7200000) {
            int r = (int)(c / 12);
            if (!bit_set(bm, r)) ntstore4(out + 4800000 + c * 4, ntload4(shs_in + c * 4));
          }
        }
      }
    }
    __builtin_amdgcn_s_setprio(1);
    mm_big8T(b0, bufB, 0, arow, khalf, a0, a1);
    __builtin_amdgcn_s_setprio(0);
    pre4(b0, ws + (size_t)(T_W2 + kq * 4) * 64, lane);
    __builtin_amdgcn_s_setprio(1);
    mm_big8T(b1, bufB, 8, arow, khalf, a0, a1);
    __builtin_amdgcn_s_setprio(0);
    store_actT(bufA, b_w1, wave, lane, a0, a1);
  }
  __syncthreads();

  // P5: H_w2 (reads A=hw)
  {
    f32x16 hacc = (f32x16)0.0f;
    pre8(b1, ws + (size_t)(T_M1 + wave * 16) * 64, lane);
    __builtin_amdgcn_s_setprio(1);
    mm_head1(b0, bufA, rg, kq, khalf, lane, hacc);
    __builtin_amdgcn_s_setprio(0);
    head_atomic<1>(wb, rg, lane, hacc);
  }
  __syncthreads();

  // P6: L_m1  B -> A ; copy pts slice (scalar) + rot slice (float4)
  {
    f32x16 a0 = (f32x16)0.0f, a1 = (f32x16)0.0f;
    pre8(b0, ws + (size_t)(T_M1 + wave * 16 + 8) * 64, lane);
    if (t < 384) {
      long long e = (long long)bid * 384 + t;
      if (e < 1800000) {
        int r = (int)(e / 3);
        if (!bit_set(bm, r))
          __builtin_nontemporal_store(__builtin_nontemporal_load(rays + e), out + e);
      }
    }
    if (t < 128) {
      long long c = (long long)bid * 128 + t;
      if (c < 600000) {
        int r = (int)c;
        if (!bit_set(bm, r)) ntstore4(out + 1800000 + c * 4, ntload4(rotq + c * 4));
      }
    }
    __builtin_amdgcn_s_setprio(1);
    mm_big8T(b1, bufB, 0, arow, khalf, a0, a1);
    __builtin_amdgcn_s_setprio(0);
    pre4(b1, ws + (size_t)(T_M2 + kq * 4) * 64, lane);
    __builtin_amdgcn_s_setprio(1);
    mm_big8T(b0, bufB, 8, arow, khalf, a0, a1);
    __builtin_amdgcn_s_setprio(0);
    store_actT(bufA, b_m1, wave, lane, a0, a1);
  }
  __syncthreads();

  // P7: H_m2 (reads A=hm) ; stage X_st -> B ; pts/opac gathers ; copy h slice
  float pr = 0.0f, hv = 0.0f;
  {
    if (t < 256) {
      int row = t >> 2, sub = t & 3;
      int g = sidx[row];
      if (sub < 3) pr = rays[(size_t)g * 3 + sub]; else hv = h_emb[g];
    }
    if (t >= 256 && t < 384) {
      long long e = (long long)bid * 128 + (t - 256);
      if (e < 600000) {
        int r = (int)e;
        if (!bit_set(bm, r))
          __builtin_nontemporal_store(__builtin_nontemporal_load(h_emb + e),
                                      out + 4200000 + e);
      }
    }
    loadX(grid_st, row0, t, bufB);
    f32x16 hacc = (f32x16)0.0f;
    __builtin_amdgcn_s_setprio(1);
    mm_head1(b1, bufA, rg, kq, khalf, lane, hacc);
    __builtin_amdgcn_s_setprio(0);
    pre8(b0, ws + (size_t)(T_ST + wave * 8) * 64, lane);
    head_atomic<1>(mub, rg, lane, hacc);
  }
  __syncthreads();

  // P8: L_st  B -> A (K=128) ; pts/opacity epilogue (NT stores)
  {
    f32x16 a0 = (f32x16)0.0f, a1 = (f32x16)0.0f;
    pre8(b1, ws + (size_t)(T_R1 + wave * 16) * 64, lane);
    __builtin_amdgcn_s_setprio(1);
    mm_big8T(b0, bufB, 0, arow, khalf, a0, a1);
    __builtin_amdgcn_s_setprio(0);
    store_actT(bufA, b_st, wave, lane, a0, a1);
    if (t < 256) {
      int row = t >> 2, sub = t & 3;
      int gr = row0 + row;
      if (gr < M_ROWS) {
        int g = sidx[row];
        if (sub < 3) {
          float mt = 1.0f - tt;
          float c0 = 3.0f * mt * mt * tt, c1 = 3.0f * mt * tt * tt, c2 = tt * tt * tt;
          float d0 = dxb[row * 9 + sub]     + b_p2[sub];
          float d1 = dxb[row * 9 + 3 + sub] + b_p2[3 + sub];
          float d2 = dxb[row * 9 + 6 + sub] + b_p2[6 + sub];
          __builtin_nontemporal_store(pr + (c0 * d0 + c1 * d1 + c2 * d2),
                                      out + (size_t)g * 3 + sub);
        } else {
          float wr = wb[row] + b_w2[0];
          float mr = mub[row] + b_m2[0];
          float mu = 1.0f / (1.0f + expf(-mr));
          float dtm = tt - mu;
          __builtin_nontemporal_store(hv * expf(-(wr * wr) * dtm * dtm),
                                      out + 4200000 + (size_t)g);
        }
      }
    }
  }
  __syncthreads();

  // P9: L_r1  A -> B (K=256)  [hr -> B; hst stays in A]
  {
    f32x16 a0 = (f32x16)0.0f, a1 = (f32x16)0.0f;
    pre8(b0, ws + (size_t)(T_R1 + wave * 16 + 8) * 64, lane);
    __builtin_amdgcn_s_setprio(1);
    mm_big8T(b1, bufA, 0, arow, khalf, a0, a1);
    __builtin_amdgcn_s_setprio(0);
    pre4(b1, ws + (size_t)(T_R2 + kq * 4) * 64, lane);
    __builtin_amdgcn_s_setprio(1);
    mm_big8T(b0, bufA, 8, arow, khalf, a0, a1);
    __builtin_amdgcn_s_setprio(0);
    store_actT(bufB, b_r1, wave, lane, a0, a1);
  }
  __syncthreads();

  // P10: H_r2 rot head (reads B=hr) -> global atomics onto P1's base
  {
    f32x16 hacc = (f32x16)0.0f;
    pre8(b0, ws + (size_t)(T_S1 + wave * 16) * 64, lane);
    __builtin_amdgcn_s_setprio(1);
    mm_head1(b1, bufB, rg, kq, khalf, lane, hacc);
    __builtin_amdgcn_s_setprio(0);
    rot_atomic_global(hacc, rg, kq, lane, sidx, row0, b_r2, out);
  }
  __syncthreads();

  // P11: L_s1  A -> B (reads hst, writes hs; hr dead)
  {
    f32x16 a0 = (f32x16)0.0f, a1 = (f32x16)0.0f;
    pre8(b1, ws + (size_t)(T_S1 + wave * 16 + 8) * 64, lane);
    __builtin_amdgcn_s_setprio(1);
    mm_big8T(b0, bufA, 0, arow, khalf, a0, a1);
    __builtin_amdgcn_s_setprio(0);
    pre_s2(b0, ws + (size_t)T_S2 * 64, kq, lane);
    __builtin_amdgcn_s_setprio(1);
    mm_big8T(b1, bufA, 8, arow, khalf, a0, a1);
    __builtin_amdgcn_s_setprio(0);
    store_actT(bufB, b_s1, wave, lane, a0, a1);
  }
  __syncthreads();

  // P12: H_s2 (reads B=hs, 2 col-tiles) -> global atomics onto P1's base; kernel ends
  {
    f32x16 h0 = (f32x16)0.0f, h1 = (f32x16)0.0f;
    const int ar = rg * 32 + (lane & 31);
    __builtin_amdgcn_s_setprio(1);
    #pragma unroll
    for (int kk = 0; kk < 4; ++kk) {
      bf16x8 a = *(const bf16x8*)(bufB + lds_addr(ar, (kq * 4 + kk) * 32 + khalf));
      h0 = __builtin_amdgcn_mfma_f32_32x32x16_bf16(a, b0[kk * 2 + 0].h, h0, 0, 0, 0);
      h1 = __builtin_amdgcn_mfma_f32_32x32x16_bf16(a, b0[kk * 2 + 1].h, h1, 0, 0, 0);
    }
    __builtin_amdgcn_s_setprio(0);
    shs_atomic_global(h0, h1, rg, kq, lane, sidx, row0, b_s2, out);
  }
}

extern "C" void kernel_launch(void* const* d_in, const int* in_sizes, int n_in,
                              void* d_out, int out_size, void* d_ws, size_t ws_size,
                              hipStream_t stream) {
  const float* rays     = (const float*)d_in[0];
  const float* rotq     = (const float*)d_in[1];
  const float* shs      = (const float*)d_in[2];
  const float* time_emb = (const float*)d_in[3];
  const float* h_emb    = (const float*)d_in[4];
  const float* grid_sp  = (const float*)d_in[5];
  const float* grid_st  = (const float*)d_in[6];
  const int*   idx      = (const int*)d_in[7];
  uint4* ws = (uint4*)d_ws;
  uint32_t* bm = (uint32_t*)((char*)d_ws + (size_t)T_TOT * 1024);   // +864 KB

  prep_w<<<T_TOT, 64, 0, stream>>>(
      (const float*)d_in[8],  (const float*)d_in[10], (const float*)d_in[12], (const float*)d_in[14],
      (const float*)d_in[16], (const float*)d_in[18], (const float*)d_in[20], (const float*)d_in[22],
      (const float*)d_in[24], (const float*)d_in[26], (const float*)d_in[28], (const float*)d_in[30],
      ws);

  bm_zero<<<75, 256, 0, stream>>>(bm);
  bm_set<<<(M_ROWS + 255) / 256, 256, 0, stream>>>(idx, bm);

  deform_main<<<NB_DEF, 512, 0, stream>>>(
      grid_sp, grid_st, idx, rays, rotq, shs, time_emb, h_emb, ws, bm,
      (const float*)d_in[9],  (const float*)d_in[11], (const float*)d_in[13], (const float*)d_in[15],
      (const float*)d_in[17], (const float*)d_in[19], (const float*)d_in[21], (const float*)d_in[23],
      (const float*)d_in[25], (const float*)d_in[27], (const float*)d_in[29], (const float*)d_in[31],
      (float*)d_out);
}

// Round 19
// 707.920 us; speedup vs baseline: 1.3341x; 1.3341x over previous
//
#include <hip/hip_runtime.h>
#include <hip/hip_bf16.h>
#include <stdint.h>

#define M_ROWS 300000

typedef __attribute__((ext_vector_type(8)))  short bf16x8;
typedef __attribute__((ext_vector_type(16))) float f32x16;
typedef __attribute__((ext_vector_type(4)))  float f32x4;

union U4 { uint4 u; bf16x8 h; unsigned short us[8]; };

__device__ __forceinline__ unsigned short f2bf(float f) {
  union { float f; uint32_t u; } v; v.f = f;
  uint32_t r = v.u + 0x7fffu + ((v.u >> 16) & 1u);
  return (unsigned short)(r >> 16);
}
__device__ __forceinline__ uint32_t pk2(float lo, float hi) {
  return (uint32_t)f2bf(lo) | ((uint32_t)f2bf(hi) << 16);
}
__device__ __forceinline__ f32x4 ntload4(const float* p) {
  return __builtin_nontemporal_load((const f32x4*)p);
}
__device__ __forceinline__ void ntstore4(float* p, f32x4 v) {
  __builtin_nontemporal_store(v, (f32x4*)p);
}

// ---- packed weight tile table (tiles of 32 cols x 16 k, 1 KiB each) ----
#define T_SP 0
#define T_ST 64
#define T_P1 128
#define T_P2 256
#define T_R1 272
#define T_R2 400
#define T_S1 416
#define T_S2 544
#define T_W1 576
#define T_W2 704
#define T_M1 720
#define T_M2 848
#define T_TOT 864

__global__ void prep_w(const float* Wsp, const float* Wst, const float* Wp1, const float* Wp2,
                       const float* Wr1, const float* Wr2, const float* Ws1, const float* Ws2,
                       const float* Ww1, const float* Ww2, const float* Wm1, const float* Wm2,
                       uint4* ws) {
  int b = blockIdx.x, l = threadIdx.x;
  const int starts[12] = {T_SP,T_ST,T_P1,T_P2,T_R1,T_R2,T_S1,T_S2,T_W1,T_W2,T_M1,T_M2};
  const int Ks[12]     = {128,128,256,256,256,256,256,256,256,256,256,256};
  const int Cos[12]    = {256,256,256,9,256,4,256,48,256,1,256,1};
  const float* Wp[12]  = {Wsp,Wst,Wp1,Wp2,Wr1,Wr2,Ws1,Ws2,Ww1,Ww2,Wm1,Wm2};
  int m = 0;
  #pragma unroll
  for (int i = 1; i < 12; ++i) if (b >= starts[i]) m = i;
  int local = b - starts[m];
  int KT = Ks[m] >> 4;
  int n0 = local / KT, k0 = local - n0 * KT;
  int col = n0 * 32 + (l & 31);
  int kbase = k0 * 16 + (l >> 5) * 8;
  const float* W = Wp[m];
  int Co = Cos[m];
  U4 pk;
  #pragma unroll
  for (int j = 0; j < 8; ++j) {
    float v = (col < Co) ? W[(size_t)(kbase + j) * Co + col] : 0.0f;
    pk.us[j] = f2bf(v);
  }
  ws[(size_t)b * 64 + l] = pk.u;
}

// ---- bulk copy of embeddings into output (non-indexed rows) ----
// NT loads everywhere (single-touch); NT stores for pts/h (set-or-dead later);
// normal stores for rot/shs (re-read by deform_main's atomic RMW).
__global__ void copy_emb(const float* pts, const float* rot, const float* h,
                         const float* shs, float* out) {
  long long stride = (long long)gridDim.x * blockDim.x;
  for (long long i = (long long)blockIdx.x * blockDim.x + threadIdx.x; i < 8400000LL; i += stride) {
    if (i < 450000) {
      ntstore4(out + i * 4, ntload4(pts + i * 4));
    } else if (i < 1050000) {
      f32x4 v = ntload4(rot + (i - 450000) * 4);
      *(f32x4*)(out + i * 4) = v;
    } else if (i < 1200000) {
      ntstore4(out + i * 4, ntload4(h + (i - 1050000) * 4));
    } else {
      f32x4 v = ntload4(shs + (i - 1200000) * 4);
      *(f32x4*)(out + i * 4) = v;
    }
  }
}

// ---- fused MLP kernel: 64 rows/block, 8 waves, swapped MFMA, direct-atomic tails ----
#define LSTR 512
__device__ __forceinline__ int lds_addr(int row, int cb) {
  return row * LSTR + (cb ^ ((row & 15) << 4));
}

__device__ __forceinline__ void loadX(const float* grid, int row0, int t, char* buf) {
  #pragma unroll
  for (int i = 0; i < 4; ++i) {
    int fi = i * 512 + t;
    int row = fi >> 5;
    int c4 = fi & 31;
    int gr = row0 + row; gr = gr < M_ROWS ? gr : (M_ROWS - 1);
    f32x4 v = ntload4(grid + (size_t)gr * 128 + c4 * 4);
    ushort4 p;
    p.x = f2bf(v.x); p.y = f2bf(v.y); p.z = f2bf(v.z); p.w = f2bf(v.w);
    *(ushort4*)(buf + lds_addr(row, c4 * 8)) = p;
  }
}

__device__ __forceinline__ void pre8(U4 (&d)[8], const uint4* base, int lane) {
  #pragma unroll
  for (int i = 0; i < 8; ++i) d[i].u = base[(size_t)i * 64 + lane];
}
__device__ __forceinline__ void pre4(U4 (&d)[8], const uint4* base, int lane) {
  #pragma unroll
  for (int i = 0; i < 4; ++i) d[i].u = base[(size_t)i * 64 + lane];
}
__device__ __forceinline__ void pre_s2(U4 (&d)[8], const uint4* wt, int kq, int lane) {
  #pragma unroll
  for (int kk = 0; kk < 4; ++kk)
    #pragma unroll
    for (int n = 0; n < 2; ++n)
      d[kk * 2 + n].u = wt[(size_t)((n * 16 + kq * 4 + kk) * 64) + lane];
}

// Swapped-operand big-layer step: D[outcol][xrow] = W_tile (A) x X^T (B).
__device__ __forceinline__ void mm_big8T(U4 (&b)[8], const char* inb, int k0, int arow, int khalf,
                                         f32x16& acc0, f32x16& acc1) {
  #pragma unroll
  for (int k = 0; k < 8; ++k) {
    bf16x8 x0 = *(const bf16x8*)(inb + lds_addr(arow, (k0 + k) * 32 + khalf));
    bf16x8 x1 = *(const bf16x8*)(inb + lds_addr(32 + arow, (k0 + k) * 32 + khalf));
    acc0 = __builtin_amdgcn_mfma_f32_32x32x16_bf16(b[k].h, x0, acc0, 0, 0, 0);
    acc1 = __builtin_amdgcn_mfma_f32_32x32x16_bf16(b[k].h, x1, acc1, 0, 0, 0);
  }
}

// Packed activation store: lane fixed xrow, outcols in runs of 4 -> ds_write_b64.
__device__ __forceinline__ void store_actT(char* outb, const float* bias, int wave, int lane,
                                           const f32x16& acc0, const f32x16& acc1) {
  const int xr = lane & 31;
  const int cb0 = wave * 32 + 4 * (lane >> 5);
  #pragma unroll
  for (int run = 0; run < 4; ++run) {
    const int c0 = cb0 + 8 * run;
    const float4 bv = *(const float4*)(bias + c0);
    uint2 w0, w1;
    w0.x = pk2(fmaxf(acc0[run * 4 + 0] + bv.x, 0.0f), fmaxf(acc0[run * 4 + 1] + bv.y, 0.0f));
    w0.y = pk2(fmaxf(acc0[run * 4 + 2] + bv.z, 0.0f), fmaxf(acc0[run * 4 + 3] + bv.w, 0.0f));
    w1.x = pk2(fmaxf(acc1[run * 4 + 0] + bv.x, 0.0f), fmaxf(acc1[run * 4 + 1] + bv.y, 0.0f));
    w1.y = pk2(fmaxf(acc1[run * 4 + 2] + bv.z, 0.0f), fmaxf(acc1[run * 4 + 3] + bv.w, 0.0f));
    *(uint2*)(outb + lds_addr(xr, c0 * 2)) = w0;
    *(uint2*)(outb + lds_addr(32 + xr, c0 * 2)) = w1;
  }
}

// MFMA head (old orientation): D[xrow][outcol], col=lane&31.
__device__ __forceinline__ void mm_head1(U4 (&b)[8], const char* inb, int rg, int kq, int khalf,
                                         int lane, f32x16& acc) {
  const int arow = rg * 32 + (lane & 31);
  #pragma unroll
  for (int kk = 0; kk < 4; ++kk) {
    bf16x8 a = *(const bf16x8*)(inb + lds_addr(arow, (kq * 4 + kk) * 32 + khalf));
    acc = __builtin_amdgcn_mfma_f32_32x32x16_bf16(a, b[kk].h, acc, 0, 0, 0);
  }
}

template<int COLS>
__device__ __forceinline__ void head_atomic(float* outsm, int rg, int lane, const f32x16& acc) {
  int col = lane & 31;
  if (col < COLS) {
    #pragma unroll
    for (int q = 0; q < 16; ++q) {
      int row = rg * 32 + (q & 3) + 8 * (q >> 2) + 4 * (lane >> 5);
      atomicAdd(&outsm[row * COLS + col], acc[q]);
    }
  }
}

// rot head -> direct global atomics onto copy_emb's rotq values (+bias once via kq==0)
__device__ __forceinline__ void rot_atomic_global(const f32x16& acc, int rg, int kq, int lane,
                                                  const int* sidx, int row0, const float* b_r2,
                                                  float* out) {
  int col = lane & 31;
  if (col < 4) {
    float bb = (kq == 0) ? b_r2[col] : 0.0f;
    #pragma unroll
    for (int q = 0; q < 16; ++q) {
      int row = rg * 32 + (q & 3) + 8 * (q >> 2) + 4 * (lane >> 5);
      if (row0 + row < M_ROWS) {
        atomicAdd(out + 1800000 + (size_t)sidx[row] * 4 + col, acc[q] + bb);
      }
    }
  }
}

// shs head -> direct global atomics onto copy_emb's shs values (+bias once via kq==0)
__device__ __forceinline__ void shs_atomic_global(const f32x16& a0, const f32x16& a1,
                                                  int rg, int kq, int lane,
                                                  const int* sidx, int row0, const float* b_s2,
                                                  float* out) {
  int c = lane & 31;
  float bb0 = (kq == 0) ? b_s2[c] : 0.0f;
  float bb1 = (kq == 0 && c < 16) ? b_s2[32 + c] : 0.0f;
  #pragma unroll
  for (int q = 0; q < 16; ++q) {
    int row = rg * 32 + (q & 3) + 8 * (q >> 2) + 4 * (lane >> 5);
    if (row0 + row < M_ROWS) {
      size_t base = 4800000 + (size_t)sidx[row] * 48;
      atomicAdd(out + base + c, a0[q] + bb0);
      if (c < 16) atomicAdd(out + base + 32 + c, a1[q] + bb1);
    }
  }
}

__global__ void __launch_bounds__(512, 4) deform_main(
    const float* grid_sp, const float* grid_st, const int* idx,
    const float* rays, const float* rotq, const float* shs_in,
    const float* time_emb, const float* h_emb,
    const uint4* ws,
    const float* b_sp, const float* b_st, const float* b_p1, const float* b_p2,
    const float* b_r1, const float* b_r2, const float* b_s1, const float* b_s2,
    const float* b_w1, const float* b_w2, const float* b_m1, const float* b_m2,
    float* out) {
  __shared__ char bufA[32768];
  __shared__ char bufB[32768];
  __shared__ float smf[704];   // dx [0,576) | w [576,640) | mu [640,704)
  __shared__ int sidx[64];
  float* dxb = smf;
  float* wb  = smf + 576;
  float* mub = smf + 640;

  const int t = threadIdx.x;
  const int lane = t & 63;
  const int wave = t >> 6;
  const int rg = wave & 1;
  const int kq = wave >> 1;
  const int arow = lane & 31;
  const int khalf = (lane >> 5) * 16;
  const int row0 = blockIdx.x * 64;
  const float tt = time_emb[0];

  U4 b0[8], b1[8];
  pre8(b0, ws + (size_t)(T_SP + wave * 8) * 64, lane);

  // P0: idx hoist, zero small accumulators, stage X_sp -> A
  if (t < 64) { int gr = row0 + t; sidx[t] = idx[gr < M_ROWS ? gr : (M_ROWS - 1)]; }
  if (t < 512) smf[t] = 0.0f;
  if (t < 192) smf[512 + t] = 0.0f;
  loadX(grid_sp, row0, t, bufA);
  __syncthreads();

  // P1: L_sp  A -> B (K=128)
  {
    f32x16 a0 = (f32x16)0.0f, a1 = (f32x16)0.0f;
    pre8(b1, ws + (size_t)(T_P1 + wave * 16) * 64, lane);
    __builtin_amdgcn_s_setprio(1);
    mm_big8T(b0, bufA, 0, arow, khalf, a0, a1);
    __builtin_amdgcn_s_setprio(0);
    store_actT(bufB, b_sp, wave, lane, a0, a1);
  }
  __syncthreads();

  // P2: L_p1  B -> A (K=256)
  {
    f32x16 a0 = (f32x16)0.0f, a1 = (f32x16)0.0f;
    pre8(b0, ws + (size_t)(T_P1 + wave * 16 + 8) * 64, lane);
    __builtin_amdgcn_s_setprio(1);
    mm_big8T(b1, bufB, 0, arow, khalf, a0, a1);
    __builtin_amdgcn_s_setprio(0);
    pre4(b1, ws + (size_t)(T_P2 + kq * 4) * 64, lane);
    __builtin_amdgcn_s_setprio(1);
    mm_big8T(b0, bufB, 8, arow, khalf, a0, a1);
    __builtin_amdgcn_s_setprio(0);
    store_actT(bufA, b_p1, wave, lane, a0, a1);
  }
  __syncthreads();

  // P3: H_p2 dx head (reads A=hp)
  {
    f32x16 hacc = (f32x16)0.0f;
    pre8(b0, ws + (size_t)(T_W1 + wave * 16) * 64, lane);
    __builtin_amdgcn_s_setprio(1);
    mm_head1(b1, bufA, rg, kq, khalf, lane, hacc);
    __builtin_amdgcn_s_setprio(0);
    head_atomic<9>(dxb, rg, lane, hacc);
  }
  __syncthreads();

  // P4: L_w1  B -> A
  {
    f32x16 a0 = (f32x16)0.0f, a1 = (f32x16)0.0f;
    pre8(b1, ws + (size_t)(T_W1 + wave * 16 + 8) * 64, lane);
    __builtin_amdgcn_s_setprio(1);
    mm_big8T(b0, bufB, 0, arow, khalf, a0, a1);
    __builtin_amdgcn_s_setprio(0);
    pre4(b0, ws + (size_t)(T_W2 + kq * 4) * 64, lane);
    __builtin_amdgcn_s_setprio(1);
    mm_big8T(b1, bufB, 8, arow, khalf, a0, a1);
    __builtin_amdgcn_s_setprio(0);
    store_actT(bufA, b_w1, wave, lane, a0, a1);
  }
  __syncthreads();

  // P5: H_w2 (reads A=hw)
  {
    f32x16 hacc = (f32x16)0.0f;
    pre8(b1, ws + (size_t)(T_M1 + wave * 16) * 64, lane);
    __builtin_amdgcn_s_setprio(1);
    mm_head1(b0, bufA, rg, kq, khalf, lane, hacc);
    __builtin_amdgcn_s_setprio(0);
    head_atomic<1>(wb, rg, lane, hacc);
  }
  __syncthreads();

  // P6: L_m1  B -> A
  {
    f32x16 a0 = (f32x16)0.0f, a1 = (f32x16)0.0f;
    pre8(b0, ws + (size_t)(T_M1 + wave * 16 + 8) * 64, lane);
    __builtin_amdgcn_s_setprio(1);
    mm_big8T(b1, bufB, 0, arow, khalf, a0, a1);
    __builtin_amdgcn_s_setprio(0);
    pre4(b1, ws + (size_t)(T_M2 + kq * 4) * 64, lane);
    __builtin_amdgcn_s_setprio(1);
    mm_big8T(b0, bufB, 8, arow, khalf, a0, a1);
    __builtin_amdgcn_s_setprio(0);
    store_actT(bufA, b_m1, wave, lane, a0, a1);
  }
  __syncthreads();

  // P7: H_m2 (reads A=hm) ; stage X_st -> B ; issue pts/opac gathers
  float pr = 0.0f, hv = 0.0f;
  {
    if (t < 256) {
      int row = t >> 2, sub = t & 3;
      int g = sidx[row];
      if (sub < 3) pr = rays[(size_t)g * 3 + sub]; else hv = h_emb[g];
    }
    loadX(grid_st, row0, t, bufB);
    f32x16 hacc = (f32x16)0.0f;
    __builtin_amdgcn_s_setprio(1);
    mm_head1(b1, bufA, rg, kq, khalf, lane, hacc);
    __builtin_amdgcn_s_setprio(0);
    pre8(b0, ws + (size_t)(T_ST + wave * 8) * 64, lane);
    head_atomic<1>(mub, rg, lane, hacc);
  }
  __syncthreads();

  // P8: L_st  B -> A (K=128) ; pts/opacity epilogue (NT stores)
  {
    f32x16 a0 = (f32x16)0.0f, a1 = (f32x16)0.0f;
    pre8(b1, ws + (size_t)(T_R1 + wave * 16) * 64, lane);
    __builtin_amdgcn_s_setprio(1);
    mm_big8T(b0, bufB, 0, arow, khalf, a0, a1);
    __builtin_amdgcn_s_setprio(0);
    store_actT(bufA, b_st, wave, lane, a0, a1);
    if (t < 256) {
      int row = t >> 2, sub = t & 3;
      int gr = row0 + row;
      if (gr < M_ROWS) {
        int g = sidx[row];
        if (sub < 3) {
          float mt = 1.0f - tt;
          float c0 = 3.0f * mt * mt * tt, c1 = 3.0f * mt * tt * tt, c2 = tt * tt * tt;
          float d0 = dxb[row * 9 + sub]     + b_p2[sub];
          float d1 = dxb[row * 9 + 3 + sub] + b_p2[3 + sub];
          float d2 = dxb[row * 9 + 6 + sub] + b_p2[6 + sub];
          __builtin_nontemporal_store(pr + (c0 * d0 + c1 * d1 + c2 * d2),
                                      out + (size_t)g * 3 + sub);
        } else {
          float wr = wb[row] + b_w2[0];
          float mr = mub[row] + b_m2[0];
          float mu = 1.0f / (1.0f + expf(-mr));
          float dtm = tt - mu;
          __builtin_nontemporal_store(hv * expf(-(wr * wr) * dtm * dtm),
                                      out + 4200000 + (size_t)g);
        }
      }
    }
  }
  __syncthreads();

  // P9: L_r1  A -> B (K=256)  [hr -> B; hst stays in A]
  {
    f32x16 a0 = (f32x16)0.0f, a1 = (f32x16)0.0f;
    pre8(b0, ws + (size_t)(T_R1 + wave * 16 + 8) * 64, lane);
    __builtin_amdgcn_s_setprio(1);
    mm_big8T(b1, bufA, 0, arow, khalf, a0, a1);
    __builtin_amdgcn_s_setprio(0);
    pre4(b1, ws + (size_t)(T_R2 + kq * 4) * 64, lane);
    __builtin_amdgcn_s_setprio(1);
    mm_big8T(b0, bufA, 8, arow, khalf, a0, a1);
    __builtin_amdgcn_s_setprio(0);
    store_actT(bufB, b_r1, wave, lane, a0, a1);
  }
  __syncthreads();

  // P10: H_r2 rot head (reads B=hr) -> direct global atomics
  {
    f32x16 hacc = (f32x16)0.0f;
    pre8(b0, ws + (size_t)(T_S1 + wave * 16) * 64, lane);
    __builtin_amdgcn_s_setprio(1);
    mm_head1(b1, bufB, rg, kq, khalf, lane, hacc);
    __builtin_amdgcn_s_setprio(0);
    rot_atomic_global(hacc, rg, kq, lane, sidx, row0, b_r2, out);
  }
  __syncthreads();

  // P11: L_s1  A -> B (reads hst, writes hs; hr dead)
  {
    f32x16 a0 = (f32x16)0.0f, a1 = (f32x16)0.0f;
    pre8(b1, ws + (size_t)(T_S1 + wave * 16 + 8) * 64, lane);
    __builtin_amdgcn_s_setprio(1);
    mm_big8T(b0, bufA, 0, arow, khalf, a0, a1);
    __builtin_amdgcn_s_setprio(0);
    pre_s2(b0, ws + (size_t)T_S2 * 64, kq, lane);
    __builtin_amdgcn_s_setprio(1);
    mm_big8T(b1, bufA, 8, arow, khalf, a0, a1);
    __builtin_amdgcn_s_setprio(0);
    store_actT(bufB, b_s1, wave, lane, a0, a1);
  }
  __syncthreads();

  // P12: H_s2 (reads B=hs, 2 col-tiles) -> direct global atomics; kernel ends
  {
    f32x16 h0 = (f32x16)0.0f, h1 = (f32x16)0.0f;
    const int ar = rg * 32 + (lane & 31);
    __builtin_amdgcn_s_setprio(1);
    #pragma unroll
    for (int kk = 0; kk < 4; ++kk) {
      bf16x8 a = *(const bf16x8*)(bufB + lds_addr(ar, (kq * 4 + kk) * 32 + khalf));
      h0 = __builtin_amdgcn_mfma_f32_32x32x16_bf16(a, b0[kk * 2 + 0].h, h0, 0, 0, 0);
      h1 = __builtin_amdgcn_mfma_f32_32x32x16_bf16(a, b0[kk * 2 + 1].h, h1, 0, 0, 0);
    }
    __builtin_amdgcn_s_setprio(0);
    shs_atomic_global(h0, h1, rg, kq, lane, sidx, row0, b_s2, out);
  }
}

extern "C" void kernel_launch(void* const* d_in, const int* in_sizes, int n_in,
                              void* d_out, int out_size, void* d_ws, size_t ws_size,
                              hipStream_t stream) {
  const float* rays     = (const float*)d_in[0];
  const float* rotq     = (const float*)d_in[1];
  const float* shs      = (const float*)d_in[2];
  const float* time_emb = (const float*)d_in[3];
  const float* h_emb    = (const float*)d_in[4];
  const float* grid_sp  = (const float*)d_in[5];
  const float* grid_st  = (const float*)d_in[6];
  const int*   idx      = (const int*)d_in[7];
  uint4* ws = (uint4*)d_ws;

  prep_w<<<T_TOT, 64, 0, stream>>>(
      (const float*)d_in[8],  (const float*)d_in[10], (const float*)d_in[12], (const float*)d_in[14],
      (const float*)d_in[16], (const float*)d_in[18], (const float*)d_in[20], (const float*)d_in[22],
      (const float*)d_in[24], (const float*)d_in[26], (const float*)d_in[28], (const float*)d_in[30],
      ws);

  copy_emb<<<2048, 256, 0, stream>>>(rays, rotq, h_emb, shs, (float*)d_out);

  deform_main<<<(M_ROWS + 63) / 64, 512, 0, stream>>>(
      grid_sp, grid_st, idx, rays, rotq, shs, time_emb, h_emb, ws,
      (const float*)d_in[9],  (const float*)d_in[11], (const float*)d_in[13], (const float*)d_in[15],
      (const float*)d_in[17], (const float*)d_in[19], (const float*)d_in[21], (const float*)d_in[23],
      (const float*)d_in[25], (const float*)d_in[27], (const float*)d_in[29], (const float*)d_in[31],
      (float*)d_out);
}

// Round 20
// 663.675 us; speedup vs baseline: 1.4230x; 1.0667x over previous
//
#include <hip/hip_runtime.h>
#include <hip/hip_bf16.h>
#include <stdint.h>

#define M_ROWS 300000

typedef __attribute__((ext_vector_type(8)))  short bf16x8;
typedef __attribute__((ext_vector_type(16))) float f32x16;
typedef __attribute__((ext_vector_type(4)))  float f32x4;

union U4 { uint4 u; bf16x8 h; unsigned short us[8]; };

__device__ __forceinline__ unsigned short f2bf(float f) {
  union { float f; uint32_t u; } v; v.f = f;
  uint32_t r = v.u + 0x7fffu + ((v.u >> 16) & 1u);
  return (unsigned short)(r >> 16);
}
__device__ __forceinline__ uint32_t pk2(float lo, float hi) {
  return (uint32_t)f2bf(lo) | ((uint32_t)f2bf(hi) << 16);
}
__device__ __forceinline__ f32x4 ntload4(const float* p) {
  return __builtin_nontemporal_load((const f32x4*)p);
}
__device__ __forceinline__ void ntstore4(float* p, f32x4 v) {
  __builtin_nontemporal_store(v, (f32x4*)p);
}

// ---- packed weight tile table (tiles of 32 cols x 16 k, 1 KiB each) ----
#define T_SP 0
#define T_ST 64
#define T_P1 128
#define T_P2 256
#define T_R1 272
#define T_R2 400
#define T_S1 416
#define T_S2 544
#define T_W1 576
#define T_W2 704
#define T_M1 720
#define T_M2 848
#define T_TOT 864

__global__ void prep_w(const float* Wsp, const float* Wst, const float* Wp1, const float* Wp2,
                       const float* Wr1, const float* Wr2, const float* Ws1, const float* Ws2,
                       const float* Ww1, const float* Ww2, const float* Wm1, const float* Wm2,
                       uint4* ws) {
  int b = blockIdx.x, l = threadIdx.x;
  const int starts[12] = {T_SP,T_ST,T_P1,T_P2,T_R1,T_R2,T_S1,T_S2,T_W1,T_W2,T_M1,T_M2};
  const int Ks[12]     = {128,128,256,256,256,256,256,256,256,256,256,256};
  const int Cos[12]    = {256,256,256,9,256,4,256,48,256,1,256,1};
  const float* Wp[12]  = {Wsp,Wst,Wp1,Wp2,Wr1,Wr2,Ws1,Ws2,Ww1,Ww2,Wm1,Wm2};
  int m = 0;
  #pragma unroll
  for (int i = 1; i < 12; ++i) if (b >= starts[i]) m = i;
  int local = b - starts[m];
  int KT = Ks[m] >> 4;
  int n0 = local / KT, k0 = local - n0 * KT;
  int col = n0 * 32 + (l & 31);
  int kbase = k0 * 16 + (l >> 5) * 8;
  const float* W = Wp[m];
  int Co = Cos[m];
  U4 pk;
  #pragma unroll
  for (int j = 0; j < 8; ++j) {
    float v = (col < Co) ? W[(size_t)(kbase + j) * Co + col] : 0.0f;
    pk.us[j] = f2bf(v);
  }
  ws[(size_t)b * 64 + l] = pk.u;
}

// ---- bulk copy of embeddings into output (non-indexed rows) ----
__global__ void copy_emb(const float* pts, const float* rot, const float* h,
                         const float* shs, float* out) {
  long long stride = (long long)gridDim.x * blockDim.x;
  for (long long i = (long long)blockIdx.x * blockDim.x + threadIdx.x; i < 8400000LL; i += stride) {
    if (i < 450000) {
      ntstore4(out + i * 4, ntload4(pts + i * 4));
    } else if (i < 1050000) {
      f32x4 v = ntload4(rot + (i - 450000) * 4);
      *(f32x4*)(out + i * 4) = v;
    } else if (i < 1200000) {
      ntstore4(out + i * 4, ntload4(h + (i - 1050000) * 4));
    } else {
      f32x4 v = ntload4(shs + (i - 1200000) * 4);
      *(f32x4*)(out + i * 4) = v;
    }
  }
}

// ---- fused MLP kernel: 32 rows/block, 8 waves, 4 blocks/CU (8 waves/SIMD) ----
#define LSTR 512
__device__ __forceinline__ int lds_addr(int row, int cb) {
  return row * LSTR + (cb ^ ((row & 15) << 4));
}

__device__ __forceinline__ void loadX(const float* grid, int row0, int t, char* buf) {
  #pragma unroll
  for (int i = 0; i < 2; ++i) {
    int fi = i * 512 + t;
    int row = fi >> 5;
    int c4 = fi & 31;
    f32x4 v = ntload4(grid + (size_t)(row0 + row) * 128 + c4 * 4);
    ushort4 p;
    p.x = f2bf(v.x); p.y = f2bf(v.y); p.z = f2bf(v.z); p.w = f2bf(v.w);
    *(ushort4*)(buf + lds_addr(row, c4 * 8)) = p;
  }
}

__device__ __forceinline__ void pre8(U4 (&d)[8], const uint4* base, int lane) {
  #pragma unroll
  for (int i = 0; i < 8; ++i) d[i].u = base[(size_t)i * 64 + lane];
}
__device__ __forceinline__ void pre4(U4 (&d)[8], const uint4* base, int lane) {
  #pragma unroll
  for (int i = 0; i < 4; ++i) d[i].u = base[(size_t)i * 64 + lane];
}
__device__ __forceinline__ void pre2(U4 (&d)[8], const uint4* base, int lane) {
  d[0].u = base[lane]; d[1].u = base[64 + lane];
}
__device__ __forceinline__ void pre_s2(U4 (&d)[8], const uint4* wt, int ct2, int kqs, int lane) {
  #pragma unroll
  for (int kk = 0; kk < 4; ++kk)
    d[kk].u = wt[(size_t)((ct2 * 16 + kqs * 4 + kk) * 64) + lane];
}

// Swapped-operand big-layer step, single 32x32 out tile.
__device__ __forceinline__ void mm_big8S(U4 (&b)[8], const char* inb, int k0, int arow, int khalf,
                                         f32x16& acc) {
  #pragma unroll
  for (int k = 0; k < 8; ++k) {
    bf16x8 x = *(const bf16x8*)(inb + lds_addr(arow, (k0 + k) * 32 + khalf));
    acc = __builtin_amdgcn_mfma_f32_32x32x16_bf16(b[k].h, x, acc, 0, 0, 0);
  }
}

// Packed activation store (single tile): lane fixed xrow, 4 runs of 4 cols -> ds_write_b64.
__device__ __forceinline__ void store_actS(char* outb, const float* bias, int wave, int lane,
                                           const f32x16& acc) {
  const int xr = lane & 31;
  const int cb0 = wave * 32 + 4 * (lane >> 5);
  #pragma unroll
  for (int run = 0; run < 4; ++run) {
    const int c0 = cb0 + 8 * run;
    const float4 bv = *(const float4*)(bias + c0);
    uint2 w;
    w.x = pk2(fmaxf(acc[run * 4 + 0] + bv.x, 0.0f), fmaxf(acc[run * 4 + 1] + bv.y, 0.0f));
    w.y = pk2(fmaxf(acc[run * 4 + 2] + bv.z, 0.0f), fmaxf(acc[run * 4 + 3] + bv.w, 0.0f));
    *(uint2*)(outb + lds_addr(xr, c0 * 2)) = w;
  }
}

// MFMA head (old orientation), 2 k-tiles (8-way k-split): D[xrow][outcol].
__device__ __forceinline__ void mm_head2t(U4 (&b)[8], const char* inb, int kq8, int khalf,
                                          int lane, f32x16& acc) {
  const int arow = lane & 31;
  bf16x8 a0 = *(const bf16x8*)(inb + lds_addr(arow, (kq8 * 2 + 0) * 32 + khalf));
  bf16x8 a1 = *(const bf16x8*)(inb + lds_addr(arow, (kq8 * 2 + 1) * 32 + khalf));
  acc = __builtin_amdgcn_mfma_f32_32x32x16_bf16(a0, b[0].h, acc, 0, 0, 0);
  acc = __builtin_amdgcn_mfma_f32_32x32x16_bf16(a1, b[1].h, acc, 0, 0, 0);
}

template<int COLS>
__device__ __forceinline__ void head_atomic(float* outsm, int lane, const f32x16& acc) {
  int col = lane & 31;
  if (col < COLS) {
    #pragma unroll
    for (int q = 0; q < 16; ++q) {
      int row = (q & 3) + 8 * (q >> 2) + 4 * (lane >> 5);
      atomicAdd(&outsm[row * COLS + col], acc[q]);
    }
  }
}

// rot head (waves 0-3, 4-way k-split) -> global atomics onto copy_emb base
__device__ __forceinline__ void rot_atomic_global(const f32x16& acc, int kq4, int lane,
                                                  const int* sidx, const float* b_r2,
                                                  float* out) {
  int col = lane & 31;
  if (col < 4) {
    float bb = (kq4 == 0) ? b_r2[col] : 0.0f;
    #pragma unroll
    for (int q = 0; q < 16; ++q) {
      int row = (q & 3) + 8 * (q >> 2) + 4 * (lane >> 5);
      atomicAdd(out + 1800000 + (size_t)sidx[row] * 4 + col, acc[q] + bb);
    }
  }
}

// shs head (col-tile ct2, k-quarter kqs) -> global atomics onto copy_emb base
__device__ __forceinline__ void shs_atomic_global(const f32x16& acc, int ct2, int kqs, int lane,
                                                  const int* sidx, const float* b_s2,
                                                  float* out) {
  int c = lane & 31;
  int col = ct2 * 32 + c;
  if (col < 48) {
    float bb = (kqs == 0) ? b_s2[col] : 0.0f;
    #pragma unroll
    for (int q = 0; q < 16; ++q) {
      int row = (q & 3) + 8 * (q >> 2) + 4 * (lane >> 5);
      atomicAdd(out + 4800000 + (size_t)sidx[row] * 48 + col, acc[q] + bb);
    }
  }
}

__global__ void __launch_bounds__(512, 4) deform_main(
    const float* grid_sp, const float* grid_st, const int* idx,
    const float* rays, const float* rotq, const float* shs_in,
    const float* time_emb, const float* h_emb,
    const uint4* ws,
    const float* b_sp, const float* b_st, const float* b_p1, const float* b_p2,
    const float* b_r1, const float* b_r2, const float* b_s1, const float* b_s2,
    const float* b_w1, const float* b_w2, const float* b_m1, const float* b_m2,
    float* out) {
  __shared__ char bufA[16384];
  __shared__ char bufB[16384];
  __shared__ float smf[352];   // dx [0,288) | w [288,320) | mu [320,352)
  __shared__ int sidx[32];
  float* dxb = smf;
  float* wb  = smf + 288;
  float* mub = smf + 320;

  const int t = threadIdx.x;
  const int lane = t & 63;
  const int wave = t >> 6;
  const int kq8 = wave;        // 8-way k-split (dx/w/mu heads)
  const int kq4 = wave & 3;    // 4-way (rot head, waves 0-3)
  const int ct2 = wave & 1;    // shs col-tile
  const int kqs = wave >> 1;   // shs k-quarter
  const int arow = lane & 31;
  const int khalf = (lane >> 5) * 16;
  const int row0 = blockIdx.x * 32;
  const float tt = time_emb[0];

  U4 b0[8], b1[8];
  pre8(b0, ws + (size_t)(T_SP + wave * 8) * 64, lane);

  // P0: idx hoist, zero small accumulators, stage X_sp -> A
  if (t < 32) sidx[t] = idx[row0 + t];
  if (t < 352) smf[t] = 0.0f;
  loadX(grid_sp, row0, t, bufA);
  __syncthreads();

  // P1: L_sp  A -> B (K=128)
  {
    f32x16 acc = (f32x16)0.0f;
    pre8(b1, ws + (size_t)(T_P1 + wave * 16) * 64, lane);
    __builtin_amdgcn_s_setprio(1);
    mm_big8S(b0, bufA, 0, arow, khalf, acc);
    __builtin_amdgcn_s_setprio(0);
    store_actS(bufB, b_sp, wave, lane, acc);
  }
  __syncthreads();

  // P2: L_p1  B -> A (K=256)
  {
    f32x16 acc = (f32x16)0.0f;
    pre8(b0, ws + (size_t)(T_P1 + wave * 16 + 8) * 64, lane);
    __builtin_amdgcn_s_setprio(1);
    mm_big8S(b1, bufB, 0, arow, khalf, acc);
    __builtin_amdgcn_s_setprio(0);
    pre2(b1, ws + (size_t)(T_P2 + kq8 * 2) * 64, lane);
    __builtin_amdgcn_s_setprio(1);
    mm_big8S(b0, bufB, 8, arow, khalf, acc);
    __builtin_amdgcn_s_setprio(0);
    store_actS(bufA, b_p1, wave, lane, acc);
  }
  __syncthreads();

  // P3: H_p2 dx head (reads A=hp, 8-way k-split, LDS atomics)
  {
    f32x16 hacc = (f32x16)0.0f;
    pre8(b0, ws + (size_t)(T_W1 + wave * 16) * 64, lane);
    __builtin_amdgcn_s_setprio(1);
    mm_head2t(b1, bufA, kq8, khalf, lane, hacc);
    __builtin_amdgcn_s_setprio(0);
    head_atomic<9>(dxb, lane, hacc);
  }
  __syncthreads();

  // P4: L_w1  B -> A
  {
    f32x16 acc = (f32x16)0.0f;
    pre8(b1, ws + (size_t)(T_W1 + wave * 16 + 8) * 64, lane);
    __builtin_amdgcn_s_setprio(1);
    mm_big8S(b0, bufB, 0, arow, khalf, acc);
    __builtin_amdgcn_s_setprio(0);
    pre2(b0, ws + (size_t)(T_W2 + kq8 * 2) * 64, lane);
    __builtin_amdgcn_s_setprio(1);
    mm_big8S(b1, bufB, 8, arow, khalf, acc);
    __builtin_amdgcn_s_setprio(0);
    store_actS(bufA, b_w1, wave, lane, acc);
  }
  __syncthreads();

  // P5: H_w2 (reads A=hw)
  {
    f32x16 hacc = (f32x16)0.0f;
    pre8(b1, ws + (size_t)(T_M1 + wave * 16) * 64, lane);
    __builtin_amdgcn_s_setprio(1);
    mm_head2t(b0, bufA, kq8, khalf, lane, hacc);
    __builtin_amdgcn_s_setprio(0);
    head_atomic<1>(wb, lane, hacc);
  }
  __syncthreads();

  // P6: L_m1  B -> A
  {
    f32x16 acc = (f32x16)0.0f;
    pre8(b0, ws + (size_t)(T_M1 + wave * 16 + 8) * 64, lane);
    __builtin_amdgcn_s_setprio(1);
    mm_big8S(b1, bufB, 0, arow, khalf, acc);
    __builtin_amdgcn_s_setprio(0);
    pre2(b1, ws + (size_t)(T_M2 + kq8 * 2) * 64, lane);
    __builtin_amdgcn_s_setprio(1);
    mm_big8S(b0, bufB, 8, arow, khalf, acc);
    __builtin_amdgcn_s_setprio(0);
    store_actS(bufA, b_m1, wave, lane, acc);
  }
  __syncthreads();

  // P7: H_m2 (reads A=hm) ; stage X_st -> B ; issue pts/opac gathers
  float pr = 0.0f, hv = 0.0f;
  {
    if (t < 128) {
      int row = t >> 2, sub = t & 3;
      int g = sidx[row];
      if (sub < 3) pr = rays[(size_t)g * 3 + sub]; else hv = h_emb[g];
    }
    loadX(grid_st, row0, t, bufB);
    f32x16 hacc = (f32x16)0.0f;
    __builtin_amdgcn_s_setprio(1);
    mm_head2t(b1, bufA, kq8, khalf, lane, hacc);
    __builtin_amdgcn_s_setprio(0);
    pre8(b0, ws + (size_t)(T_ST + wave * 8) * 64, lane);
    head_atomic<1>(mub, lane, hacc);
  }
  __syncthreads();

  // P8: L_st  B -> A (K=128) ; pts/opacity epilogue (NT stores)
  {
    f32x16 acc = (f32x16)0.0f;
    pre8(b1, ws + (size_t)(T_R1 + wave * 16) * 64, lane);
    __builtin_amdgcn_s_setprio(1);
    mm_big8S(b0, bufB, 0, arow, khalf, acc);
    __builtin_amdgcn_s_setprio(0);
    store_actS(bufA, b_st, wave, lane, acc);
    if (t < 128) {
      int row = t >> 2, sub = t & 3;
      int g = sidx[row];
      if (sub < 3) {
        float mt = 1.0f - tt;
        float c0 = 3.0f * mt * mt * tt, c1 = 3.0f * mt * tt * tt, c2 = tt * tt * tt;
        float d0 = dxb[row * 9 + sub]     + b_p2[sub];
        float d1 = dxb[row * 9 + 3 + sub] + b_p2[3 + sub];
        float d2 = dxb[row * 9 + 6 + sub] + b_p2[6 + sub];
        __builtin_nontemporal_store(pr + (c0 * d0 + c1 * d1 + c2 * d2),
                                    out + (size_t)g * 3 + sub);
      } else {
        float wr = wb[row] + b_w2[0];
        float mr = mub[row] + b_m2[0];
        float mu = 1.0f / (1.0f + expf(-mr));
        float dtm = tt - mu;
        __builtin_nontemporal_store(hv * expf(-(wr * wr) * dtm * dtm),
                                    out + 4200000 + (size_t)g);
      }
    }
  }
  __syncthreads();

  // P9: L_r1  A -> B (K=256)  [hr -> B; hst stays in A]
  {
    f32x16 acc = (f32x16)0.0f;
    pre8(b0, ws + (size_t)(T_R1 + wave * 16 + 8) * 64, lane);
    __builtin_amdgcn_s_setprio(1);
    mm_big8S(b1, bufA, 0, arow, khalf, acc);
    __builtin_amdgcn_s_setprio(0);
    pre4(b1, ws + (size_t)(T_R2 + kq4 * 4) * 64, lane);
    __builtin_amdgcn_s_setprio(1);
    mm_big8S(b0, bufA, 8, arow, khalf, acc);
    __builtin_amdgcn_s_setprio(0);
    store_actS(bufB, b_r1, wave, lane, acc);
  }
  __syncthreads();

  // P10: H_r2 rot head (reads B=hr, waves 0-3, 4 k-tiles each) -> global atomics
  {
    if (wave < 4) {
      f32x16 hacc = (f32x16)0.0f;
      const int ar = lane & 31;
      __builtin_amdgcn_s_setprio(1);
      #pragma unroll
      for (int kk = 0; kk < 4; ++kk) {
        bf16x8 a = *(const bf16x8*)(bufB + lds_addr(ar, (kq4 * 4 + kk) * 32 + khalf));
        hacc = __builtin_amdgcn_mfma_f32_32x32x16_bf16(a, b1[kk].h, hacc, 0, 0, 0);
      }
      __builtin_amdgcn_s_setprio(0);
      rot_atomic_global(hacc, kq4, lane, sidx, b_r2, out);
    }
    pre8(b0, ws + (size_t)(T_S1 + wave * 16) * 64, lane);
  }
  __syncthreads();

  // P11: L_s1  A -> B (reads hst, writes hs; hr dead)
  {
    f32x16 acc = (f32x16)0.0f;
    pre8(b1, ws + (size_t)(T_S1 + wave * 16 + 8) * 64, lane);
    __builtin_amdgcn_s_setprio(1);
    mm_big8S(b0, bufA, 0, arow, khalf, acc);
    __builtin_amdgcn_s_setprio(0);
    pre_s2(b0, ws + (size_t)T_S2 * 64, ct2, kqs, lane);
    __builtin_amdgcn_s_setprio(1);
    mm_big8S(b1, bufA, 8, arow, khalf, acc);
    __builtin_amdgcn_s_setprio(0);
    store_actS(bufB, b_s1, wave, lane, acc);
  }
  __syncthreads();

  // P12: H_s2 (reads B=hs; col-tile ct2, k-quarter kqs) -> global atomics; kernel ends
  {
    f32x16 hacc = (f32x16)0.0f;
    const int ar = lane & 31;
    __builtin_amdgcn_s_setprio(1);
    #pragma unroll
    for (int kk = 0; kk < 4; ++kk) {
      bf16x8 a = *(const bf16x8*)(bufB + lds_addr(ar, (kqs * 4 + kk) * 32 + khalf));
      hacc = __builtin_amdgcn_mfma_f32_32x32x16_bf16(a, b0[kk].h, hacc, 0, 0, 0);
    }
    __builtin_amdgcn_s_setprio(0);
    shs_atomic_global(hacc, ct2, kqs, lane, sidx, b_s2, out);
  }
}

extern "C" void kernel_launch(void* const* d_in, const int* in_sizes, int n_in,
                              void* d_out, int out_size, void* d_ws, size_t ws_size,
                              hipStream_t stream) {
  const float* rays     = (const float*)d_in[0];
  const float* rotq     = (const float*)d_in[1];
  const float* shs      = (const float*)d_in[2];
  const float* time_emb = (const float*)d_in[3];
  const float* h_emb    = (const float*)d_in[4];
  const float* grid_sp  = (const float*)d_in[5];
  const float* grid_st  = (const float*)d_in[6];
  const int*   idx      = (const int*)d_in[7];
  uint4* ws = (uint4*)d_ws;

  prep_w<<<T_TOT, 64, 0, stream>>>(
      (const float*)d_in[8],  (const float*)d_in[10], (const float*)d_in[12], (const float*)d_in[14],
      (const float*)d_in[16], (const float*)d_in[18], (const float*)d_in[20], (const float*)d_in[22],
      (const float*)d_in[24], (const float*)d_in[26], (const float*)d_in[28], (const float*)d_in[30],
      ws);

  copy_emb<<<2048, 256, 0, stream>>>(rays, rotq, h_emb, shs, (float*)d_out);

  deform_main<<<M_ROWS / 32, 512, 0, stream>>>(
      grid_sp, grid_st, idx, rays, rotq, shs, time_emb, h_emb, ws,
      (const float*)d_in[9],  (const float*)d_in[11], (const float*)d_in[13], (const float*)d_in[15],
      (const float*)d_in[17], (const float*)d_in[19], (const float*)d_in[21], (const float*)d_in[23],
      (const float*)d_in[25], (const float*)d_in[27], (const float*)d_in[29], (const float*)d_in[31],
      (float*)d_out);
}